// Round 15
// baseline (311.739 us; speedup 1.0000x reference)
//
#include <hip/hip_runtime.h>
#include <math.h>

// Channelatt: x(32,256,56,56) f32 -> x * sigmoid(gate(n,c))
// 4-kernel pipeline: k1 logits partials -> k2 softmax -> k3 stats+GATE
// (last-block-per-n finisher, agent-scope atomics, no fences) -> k5 scale.
// Ledger (measured R10-R14): k1~15-20, k2~4, k3~5.5, k4-was~3, k5~31
// (copy ceiling), gaps ~5/boundary -> this round removes one boundary.

#define N_ 32
#define C_ 256
#define H_ 56
#define W_ 56
#define S_ 3136   // H_*W_
#define Q_ 784    // S_/4 (float4 units)
#define LN_EPS 1e-5f

#define NCH 16    // c-chunks in pass 1
#define CPC 16    // channels per chunk (NCH*CPC == C_)
#define SQ  4     // s-chunks in pass 1
#define QCH 196   // f4 per s-chunk (Q_/SQ)

using f4 = __attribute__((ext_vector_type(4))) float;

__device__ __forceinline__ float wave_sum(float v) {
  #pragma unroll
  for (int o = 32; o > 0; o >>= 1) v += __shfl_xor(v, o);
  return v;
}
__device__ __forceinline__ float wave_max(float v) {
  #pragma unroll
  for (int o = 32; o > 0; o >>= 1) v = fmaxf(v, __shfl_xor(v, o));
  return v;
}
__device__ __forceinline__ float block_sum(float v, float* red) {
  int lane = threadIdx.x & 63, wid = threadIdx.x >> 6;
  float w = wave_sum(v);
  __syncthreads();
  if (lane == 0) red[wid] = w;
  __syncthreads();
  return red[0] + red[1] + red[2] + red[3];
}
__device__ __forceinline__ float dot4(f4 a, f4 b) {
  return a.x * b.x + a.y * b.y + a.z * b.z + a.w * b.w;
}
__device__ __forceinline__ float max4(f4 a) {
  return fmaxf(fmaxf(a.x, a.y), fmaxf(a.z, a.w));
}

// K1: partial logits. Block = (c-chunk, n, s-chunk) = 2048 blocks.
__global__ __launch_bounds__(256)
void k_logits(const float* __restrict__ x, const float* __restrict__ gc_w,
              float* __restrict__ lpart) {
  int ch = blockIdx.x, n = blockIdx.y, sq = blockIdx.z;
  int tid = threadIdx.x;
  int c0 = ch * CPC;
  if (tid >= QCH) return;
  int q = sq * QCH + tid;
  const f4* xb = (const f4*)x + ((size_t)n * C_ + c0) * Q_ + q;
  f4 A = {0,0,0,0};
  #pragma unroll
  for (int c = 0; c < CPC; ++c) A += gc_w[c0 + c] * xb[(size_t)c * Q_];
  ((f4*)lpart)[((size_t)n * NCH + ch) * Q_ + q] = A;
}

// K2: fold 16 partials -> softmax over s per n. One block per n, float4.
__global__ void k_softmax(const float* __restrict__ lpart, float* __restrict__ attn) {
  int n = blockIdx.x, tid = threadIdx.x;
  __shared__ float red[4];
  const f4* lp = (const f4*)lpart + (size_t)n * NCH * Q_;
  f4 v[4];
  float m = -INFINITY;
  #pragma unroll
  for (int k = 0; k < 3; ++k) {
    int q = tid + k * 256;
    f4 acc = {0,0,0,0};
    #pragma unroll
    for (int ch = 0; ch < NCH; ++ch) acc += lp[(size_t)ch * Q_ + q];
    v[k] = acc;
    m = fmaxf(m, max4(acc));
  }
  if (tid < 16) {
    f4 acc = {0,0,0,0};
    #pragma unroll
    for (int ch = 0; ch < NCH; ++ch) acc += lp[(size_t)ch * Q_ + 768 + tid];
    v[3] = acc;
    m = fmaxf(m, max4(acc));
  } else {
    v[3] = f4{-INFINITY, -INFINITY, -INFINITY, -INFINITY};
  }
  float wm = wave_max(m);
  int lane = tid & 63, wid = tid >> 6;
  if (lane == 0) red[wid] = wm;
  __syncthreads();
  m = fmaxf(fmaxf(red[0], red[1]), fmaxf(red[2], red[3]));
  float z = 0.f;
  #pragma unroll
  for (int k = 0; k < 4; ++k) {
    v[k].x = expf(v[k].x - m); v[k].y = expf(v[k].y - m);
    v[k].z = expf(v[k].z - m); v[k].w = expf(v[k].w - m);
    z += v[k].x + v[k].y + v[k].z + v[k].w;   // exp(-inf)=0 for tail lanes
  }
  z = block_sum(z, red);
  float inv = 1.f / z;
  f4* ap = (f4*)attn + (size_t)n * Q_;
  #pragma unroll
  for (int k = 0; k < 3; ++k) ap[tid + k * 256] = v[k] * inv;
  if (tid < 16) ap[768 + tid] = v[3] * inv;
}

// K3: per (n,c): x_g, x_max, x_dct (warm x pass, 8192 blocks) + FUSED GATE:
// the 256th block to finish each n (agent-scope atomic counter) computes the
// whole gate row. Cross-block data goes through agent-scope atomics (sc-bit
// coherence-point access) -> no __threadfence, no L2-flush storm (R5 lesson).
__global__ void k_stats_gate(const float* __restrict__ x, const float* __restrict__ attn,
                             float* __restrict__ xg, float* __restrict__ xmax,
                             float* __restrict__ xdct, unsigned* __restrict__ cnt,
                             const float* __restrict__ lc_w, const float* __restrict__ lc_b,
                             const float* __restrict__ lcln_g, const float* __restrict__ lcln_b,
                             const float* __restrict__ tw_w, const float* __restrict__ tw_b,
                             const float* __restrict__ twln_g, const float* __restrict__ twln_b,
                             const float* __restrict__ wdct, const float* __restrict__ wmax,
                             float* __restrict__ gate) {
  int c = blockIdx.x, n = blockIdx.y, tid = threadIdx.x;
  __shared__ float bh[H_];
  __shared__ f4 bw4[14];
  __shared__ float red3[3][4];
  __shared__ bool fin_s;
  int grp = c >> 6;
  int u = grp >> 1, vv = grp & 1;
  const float invs = 0.13363062f;   // 1/sqrt(56)
  const float sq2  = 1.41421356f;
  if (tid < H_) {
    float b = cosf((float)M_PI * u * (tid + 0.5f) / H_) * invs;
    bh[tid] = u ? b * sq2 : b;
  } else if (tid >= 64 && tid < 64 + 14) {
    int j = tid - 64;
    f4 b;
    #pragma unroll
    for (int e = 0; e < 4; ++e) {
      float t = cosf((float)M_PI * vv * (4 * j + e + 0.5f) / W_) * invs;
      ((float*)&b)[e] = vv ? t * sq2 : t;
    }
    bw4[j] = b;
  }
  __syncthreads();
  const f4* xp = (const f4*)(x + ((size_t)n * C_ + c) * S_);
  const f4* ap = (const f4*)(attn + (size_t)n * S_);
  float g = 0.f, d = 0.f, mx = -INFINITY;
  #pragma unroll
  for (int k = 0; k < 3; ++k) {
    int q = tid + k * 256;
    f4 xv = xp[q], av = ap[q];
    g += dot4(xv, av);
    mx = fmaxf(max4(xv), mx);
    int h = q / 14;
    d += bh[h] * dot4(xv, bw4[q - h * 14]);
  }
  if (tid < 16) {
    int q = 768 + tid;
    f4 xv = xp[q], av = ap[q];
    g += dot4(xv, av);
    mx = fmaxf(max4(xv), mx);
    int h = q / 14;
    d += bh[h] * dot4(xv, bw4[q - h * 14]);
  }
  float gs = wave_sum(g), ms = wave_max(mx), ds = wave_sum(d);
  int lane = tid & 63, wid = tid >> 6;
  if (lane == 0) { red3[0][wid] = gs; red3[1][wid] = ms; red3[2][wid] = ds; }
  __syncthreads();
  if (tid == 0) {
    float xgv = red3[0][0] + red3[0][1] + red3[0][2] + red3[0][3];
    float xmv = fmaxf(fmaxf(red3[1][0], red3[1][1]), fmaxf(red3[1][2], red3[1][3]));
    float xdv = red3[2][0] + red3[2][1] + red3[2][2] + red3[2][3];
    __hip_atomic_store(&xg[n * C_ + c],   xgv, __ATOMIC_RELAXED, __HIP_MEMORY_SCOPE_AGENT);
    __hip_atomic_store(&xmax[n * C_ + c], xmv, __ATOMIC_RELAXED, __HIP_MEMORY_SCOPE_AGENT);
    __hip_atomic_store(&xdct[n * C_ + c], xdv, __ATOMIC_RELAXED, __HIP_MEMORY_SCOPE_AGENT);
    unsigned prev = __hip_atomic_fetch_add(&cnt[n], 1u, __ATOMIC_ACQ_REL,
                                           __HIP_MEMORY_SCOPE_AGENT);
    fin_s = (prev == C_ - 1);
  }
  __syncthreads();
  if (!fin_s) return;

  // ---- finisher: gate row for this n (k4 body, 256 threads) ----
  __shared__ float xs[C_ + 2];
  __shared__ float att_s[C_];
  __shared__ float att2_s[C_];
  __shared__ float red[4];
  int cc = tid;
  float gv = __hip_atomic_load(&xg[n * C_ + cc],   __ATOMIC_RELAXED, __HIP_MEMORY_SCOPE_AGENT);
  float mv = __hip_atomic_load(&xmax[n * C_ + cc], __ATOMIC_RELAXED, __HIP_MEMORY_SCOPE_AGENT);
  float dv0 = __hip_atomic_load(&xdct[n * C_ + cc], __ATOMIC_RELAXED, __HIP_MEMORY_SCOPE_AGENT);
  float sv = wmax[cc] * mv + wdct[cc] * dv0;
  xs[cc + 1] = sv;
  if (cc == 0) { xs[0] = 0.f; xs[C_ + 1] = 0.f; }
  __syncthreads();
  float xl = lc_w[0] * xs[cc] + lc_w[1] * xs[cc + 1] + lc_w[2] * xs[cc + 2] + lc_b[0];
  float t = gv + sv + xl;
  float mu  = block_sum(t, red) * (1.f / C_);
  float dv  = t - mu;
  float var = block_sum(dv * dv, red) * (1.f / C_);
  att_s[cc] = dv * rsqrtf(var + LN_EPS) * lcln_g[cc] + lcln_b[cc];
  __syncthreads();
  // matmul: 4 threads/row, 4 passes of 64 rows (coalesced 64B segments, ILP)
  {
    int r4 = tid >> 2, j = tid & 3;
    const f4* a4 = (const f4*)att_s;
    #pragma unroll
    for (int p = 0; p < 4; ++p) {
      int row = p * 64 + r4;
      const f4* twr = (const f4*)tw_w + (size_t)row * 64;
      float acc = 0.f;
      #pragma unroll
      for (int k16 = 0; k16 < 16; ++k16)
        acc += dot4(twr[k16 * 4 + j], a4[k16 * 4 + j]);
      acc += __shfl_xor(acc, 1);
      acc += __shfl_xor(acc, 2);
      if (j == 0) att2_s[row] = acc;
    }
  }
  __syncthreads();
  float a2 = att2_s[cc] + tw_b[cc];
  float mu2  = block_sum(a2, red) * (1.f / C_);
  float d2   = a2 - mu2;
  float var2 = block_sum(d2 * d2, red) * (1.f / C_);
  float z = d2 * rsqrtf(var2 + LN_EPS) * twln_g[cc] + twln_b[cc];
  gate[n * C_ + cc] = 1.f / (1.f + expf(-z));   // consumed after kernel boundary
}

// K5: out = x * gate[n,c], float4 grid-stride, NT stores.
__global__ void k_scale(const float* __restrict__ x, const float* __restrict__ gate,
                        float* __restrict__ out) {
  const f4* x4 = (const f4*)x;
  f4* o4 = (f4*)out;
  const int total = N_ * C_ * Q_;
  for (int i = blockIdx.x * blockDim.x + threadIdx.x; i < total;
       i += gridDim.x * blockDim.x) {
    int nc = i / Q_;
    float gv = gate[nc];
    f4 v = x4[i];
    v *= gv;
    __builtin_nontemporal_store(v, &o4[i]);
  }
}

extern "C" void kernel_launch(void* const* d_in, const int* in_sizes, int n_in,
                              void* d_out, int out_size, void* d_ws, size_t ws_size,
                              hipStream_t stream) {
  const float* x      = (const float*)d_in[0];
  const float* gc_w   = (const float*)d_in[1];
  // d_in[2] = gc_b: softmax shift-invariant, unused
  const float* lc_w   = (const float*)d_in[3];
  const float* lc_b   = (const float*)d_in[4];
  const float* lcln_g = (const float*)d_in[5];
  const float* lcln_b = (const float*)d_in[6];
  const float* tw_w   = (const float*)d_in[7];
  const float* tw_b   = (const float*)d_in[8];
  const float* twln_g = (const float*)d_in[9];
  const float* twln_b = (const float*)d_in[10];
  const float* wdct   = (const float*)d_in[11];
  const float* wmax   = (const float*)d_in[12];
  float* out = (float*)d_out;

  float* ws    = (float*)d_ws;
  unsigned* cnt = (unsigned*)ws;                       // [64] slots reserved
  float* lpart = ws + 64;                              // NCH*N*S
  float* attn  = lpart + (size_t)NCH * N_ * S_;        // N*S
  float* xg    = attn + (size_t)N_ * S_;               // N*C
  float* xmax_ = xg + N_ * C_;
  float* xdct_ = xmax_ + N_ * C_;
  float* gate  = xdct_ + N_ * C_;

  (void)hipMemsetAsync(cnt, 0, 256, stream);
  hipLaunchKernelGGL(k_logits, dim3(NCH, N_, SQ), dim3(256), 0, stream, x, gc_w, lpart);
  hipLaunchKernelGGL(k_softmax, dim3(N_), dim3(256), 0, stream, lpart, attn);
  hipLaunchKernelGGL(k_stats_gate, dim3(C_, N_), dim3(256), 0, stream,
                     x, attn, xg, xmax_, xdct_, cnt,
                     lc_w, lc_b, lcln_g, lcln_b, tw_w, tw_b,
                     twln_g, twln_b, wdct, wmax, gate);
  hipLaunchKernelGGL(k_scale, dim3(2048), dim3(256), 0, stream, x, gate, out);
}

// Round 16
// 82.108 us; speedup vs baseline: 3.7967x; 3.7967x over previous
//
#include <hip/hip_runtime.h>
#include <math.h>

// Channelatt: x(32,256,56,56) f32 -> x * sigmoid(gate(n,c))
// 5-kernel serial chain (structurally forced: each kernel consumes a complete
// reduction). R5/R15 lesson: NO cross-block coherence inside kernels on CDNA4
// (fences & acq/rel agent atomics = L2 flush storms); kernel boundary is the
// only cheap device barrier.
// Ledger: k1~16-20 (cold HBM read, at floor), k2~4, k3~5.5 (L3-fed), k4~3
// (1024-thr coalesced), k5~31 (pure HBM write @3.3TB/s). This round: k5
// row-block structure (no int div, 8192 blocks).

#define N_ 32
#define C_ 256
#define H_ 56
#define W_ 56
#define S_ 3136   // H_*W_
#define Q_ 784    // S_/4 (float4 units)
#define LN_EPS 1e-5f

#define NCH 16    // c-chunks in pass 1
#define CPC 16    // channels per chunk (NCH*CPC == C_)
#define SQ  4     // s-chunks in pass 1
#define QCH 196   // f4 per s-chunk (Q_/SQ)

using f4 = __attribute__((ext_vector_type(4))) float;

__device__ __forceinline__ float wave_sum(float v) {
  #pragma unroll
  for (int o = 32; o > 0; o >>= 1) v += __shfl_xor(v, o);
  return v;
}
__device__ __forceinline__ float wave_max(float v) {
  #pragma unroll
  for (int o = 32; o > 0; o >>= 1) v = fmaxf(v, __shfl_xor(v, o));
  return v;
}
// 256-thread block sum (4 waves)
__device__ __forceinline__ float block_sum(float v, float* red) {
  int lane = threadIdx.x & 63, wid = threadIdx.x >> 6;
  float w = wave_sum(v);
  __syncthreads();
  if (lane == 0) red[wid] = w;
  __syncthreads();
  return red[0] + red[1] + red[2] + red[3];
}
// 1024-thread block sum (16 waves)
__device__ __forceinline__ float block_sum16(float v, float* red) {
  int lane = threadIdx.x & 63, wid = threadIdx.x >> 6;
  float w = wave_sum(v);
  __syncthreads();
  if (lane == 0) red[wid] = w;
  __syncthreads();
  float s = 0.f;
  #pragma unroll
  for (int i = 0; i < 16; ++i) s += red[i];
  return s;
}
__device__ __forceinline__ float dot4(f4 a, f4 b) {
  return a.x * b.x + a.y * b.y + a.z * b.z + a.w * b.w;
}
__device__ __forceinline__ float max4(f4 a) {
  return fmaxf(fmaxf(a.x, a.y), fmaxf(a.z, a.w));
}

// K1: partial logits. Block = (c-chunk, n, s-chunk) = 2048 blocks.
__global__ __launch_bounds__(256)
void k_logits(const float* __restrict__ x, const float* __restrict__ gc_w,
              float* __restrict__ lpart) {
  int ch = blockIdx.x, n = blockIdx.y, sq = blockIdx.z;
  int tid = threadIdx.x;
  int c0 = ch * CPC;
  if (tid >= QCH) return;
  int q = sq * QCH + tid;
  const f4* xb = (const f4*)x + ((size_t)n * C_ + c0) * Q_ + q;
  f4 A = {0,0,0,0};
  #pragma unroll
  for (int c = 0; c < CPC; ++c) A += gc_w[c0 + c] * xb[(size_t)c * Q_];
  ((f4*)lpart)[((size_t)n * NCH + ch) * Q_ + q] = A;
}

// K2: fold 16 partials -> softmax over s per n. One block per n, float4.
__global__ void k_softmax(const float* __restrict__ lpart, float* __restrict__ attn) {
  int n = blockIdx.x, tid = threadIdx.x;
  __shared__ float red[4];
  const f4* lp = (const f4*)lpart + (size_t)n * NCH * Q_;
  f4 v[4];
  float m = -INFINITY;
  #pragma unroll
  for (int k = 0; k < 3; ++k) {
    int q = tid + k * 256;
    f4 acc = {0,0,0,0};
    #pragma unroll
    for (int ch = 0; ch < NCH; ++ch) acc += lp[(size_t)ch * Q_ + q];
    v[k] = acc;
    m = fmaxf(m, max4(acc));
  }
  if (tid < 16) {
    f4 acc = {0,0,0,0};
    #pragma unroll
    for (int ch = 0; ch < NCH; ++ch) acc += lp[(size_t)ch * Q_ + 768 + tid];
    v[3] = acc;
    m = fmaxf(m, max4(acc));
  } else {
    v[3] = f4{-INFINITY, -INFINITY, -INFINITY, -INFINITY};
  }
  float wm = wave_max(m);
  int lane = tid & 63, wid = tid >> 6;
  if (lane == 0) red[wid] = wm;
  __syncthreads();
  m = fmaxf(fmaxf(red[0], red[1]), fmaxf(red[2], red[3]));
  float z = 0.f;
  #pragma unroll
  for (int k = 0; k < 4; ++k) {
    v[k].x = expf(v[k].x - m); v[k].y = expf(v[k].y - m);
    v[k].z = expf(v[k].z - m); v[k].w = expf(v[k].w - m);
    z += v[k].x + v[k].y + v[k].z + v[k].w;   // exp(-inf)=0 for tail lanes
  }
  z = block_sum(z, red);
  float inv = 1.f / z;
  f4* ap = (f4*)attn + (size_t)n * Q_;
  #pragma unroll
  for (int k = 0; k < 3; ++k) ap[tid + k * 256] = v[k] * inv;
  if (tid < 16) ap[768 + tid] = v[3] * inv;
}

// K3: per (n,c): x_g, x_max, x_dct in one warm x pass. Block per (c,n) = 8192.
__global__ void k_stats(const float* __restrict__ x, const float* __restrict__ attn,
                        float* __restrict__ xg, float* __restrict__ xmax,
                        float* __restrict__ xdct) {
  int c = blockIdx.x, n = blockIdx.y, tid = threadIdx.x;
  __shared__ float bh[H_];
  __shared__ f4 bw4[14];
  __shared__ float red[3][4];
  int grp = c >> 6;
  int u = grp >> 1, vv = grp & 1;
  const float invs = 0.13363062f;   // 1/sqrt(56)
  const float sq2  = 1.41421356f;
  if (tid < H_) {
    float b = cosf((float)M_PI * u * (tid + 0.5f) / H_) * invs;
    bh[tid] = u ? b * sq2 : b;
  } else if (tid >= 64 && tid < 64 + 14) {
    int j = tid - 64;
    f4 b;
    #pragma unroll
    for (int e = 0; e < 4; ++e) {
      float t = cosf((float)M_PI * vv * (4 * j + e + 0.5f) / W_) * invs;
      ((float*)&b)[e] = vv ? t * sq2 : t;
    }
    bw4[j] = b;
  }
  __syncthreads();
  const f4* xp = (const f4*)(x + ((size_t)n * C_ + c) * S_);
  const f4* ap = (const f4*)(attn + (size_t)n * S_);
  float g = 0.f, d = 0.f, mx = -INFINITY;
  #pragma unroll
  for (int k = 0; k < 3; ++k) {
    int q = tid + k * 256;
    f4 xv = xp[q], av = ap[q];
    g += dot4(xv, av);
    mx = fmaxf(max4(xv), mx);
    int h = q / 14;
    d += bh[h] * dot4(xv, bw4[q - h * 14]);
  }
  if (tid < 16) {
    int q = 768 + tid;
    f4 xv = xp[q], av = ap[q];
    g += dot4(xv, av);
    mx = fmaxf(max4(xv), mx);
    int h = q / 14;
    d += bh[h] * dot4(xv, bw4[q - h * 14]);
  }
  float gs = wave_sum(g), ms = wave_max(mx), ds = wave_sum(d);
  int lane = tid & 63, wid = tid >> 6;
  if (lane == 0) { red[0][wid] = gs; red[1][wid] = ms; red[2][wid] = ds; }
  __syncthreads();
  if (tid == 0) {
    xg[n * C_ + c]   = red[0][0] + red[0][1] + red[0][2] + red[0][3];
    xmax[n * C_ + c] = fmaxf(fmaxf(red[1][0], red[1][1]), fmaxf(red[1][2], red[1][3]));
    xdct[n * C_ + c] = red[2][0] + red[2][1] + red[2][2] + red[2][3];
  }
}

// K4: per-n gate math, 1024 threads (16 waves/CU on 32 CUs), R14-proven.
__global__ __launch_bounds__(1024)
void k_gate(const float* __restrict__ xg, const float* __restrict__ xmax,
            const float* __restrict__ xdct,
            const float* __restrict__ lc_w, const float* __restrict__ lc_b,
            const float* __restrict__ lcln_g, const float* __restrict__ lcln_b,
            const float* __restrict__ tw_w, const float* __restrict__ tw_b,
            const float* __restrict__ twln_g, const float* __restrict__ twln_b,
            const float* __restrict__ wdct, const float* __restrict__ wmax,
            float* __restrict__ gate) {
  int n = blockIdx.x, tid = threadIdx.x;
  const bool active = tid < C_;
  __shared__ float xs[C_ + 2];
  __shared__ float att_s[C_];
  __shared__ float att2_s[C_];
  __shared__ float red[16];
  float t = 0.f;
  if (active) {
    int c = tid;
    float g  = xg[n * C_ + c];
    float sv = wmax[c] * xmax[n * C_ + c] + wdct[c] * xdct[n * C_ + c];
    xs[c + 1] = sv;
    if (c == 0) { xs[0] = 0.f; xs[C_ + 1] = 0.f; }
    t = g + sv;   // xl added after barrier
  }
  __syncthreads();
  if (active) {
    int c = tid;
    t += lc_w[0] * xs[c] + lc_w[1] * xs[c + 1] + lc_w[2] * xs[c + 2] + lc_b[0];
  }
  float mu  = block_sum16(active ? t : 0.f, red) * (1.f / C_);
  float dv  = t - mu;
  float var = block_sum16(active ? dv * dv : 0.f, red) * (1.f / C_);
  if (active) {
    int c = tid;
    att_s[c] = dv * rsqrtf(var + LN_EPS) * lcln_g[c] + lcln_b[c];
  }
  __syncthreads();
  // matmul: att2_s[row] = dot(tw_w[row], att_s); row = tid>>2, j = tid&3.
  {
    int row = tid >> 2, j = tid & 3;
    const f4* twr = (const f4*)tw_w + (size_t)row * 64;
    const f4* a4  = (const f4*)att_s;
    float acc = 0.f;
    #pragma unroll
    for (int k16 = 0; k16 < 16; ++k16)
      acc += dot4(twr[k16 * 4 + j], a4[k16 * 4 + j]);
    acc += __shfl_xor(acc, 1);
    acc += __shfl_xor(acc, 2);
    if (j == 0) att2_s[row] = acc;
  }
  __syncthreads();
  float a2 = active ? att2_s[tid] + tw_b[tid] : 0.f;
  float mu2  = block_sum16(active ? a2 : 0.f, red) * (1.f / C_);
  float d2   = a2 - mu2;
  float var2 = block_sum16(active ? d2 * d2 : 0.f, red) * (1.f / C_);
  if (active) {
    int c = tid;
    float z = d2 * rsqrtf(var2 + LN_EPS) * twln_g[c] + twln_b[c];
    gate[n * C_ + c] = 1.f / (1.f + expf(-z));
  }
}

// K5: out = x * gate[n,c]. Block per (c,n) row: gate loaded once, affine
// q-indices (no int div), NT stores (write-bound: 103MB @ ~3.3TB/s).
__global__ __launch_bounds__(256)
void k_scale(const float* __restrict__ x, const float* __restrict__ gate,
             float* __restrict__ out) {
  int c = blockIdx.x, n = blockIdx.y, tid = threadIdx.x;
  float gv = gate[n * C_ + c];
  const f4* xp = (const f4*)x + ((size_t)n * C_ + c) * Q_;
  f4* op = (f4*)out + ((size_t)n * C_ + c) * Q_;
  f4 v0 = xp[tid], v1 = xp[tid + 256], v2 = xp[tid + 512];
  __builtin_nontemporal_store(v0 * gv, &op[tid]);
  __builtin_nontemporal_store(v1 * gv, &op[tid + 256]);
  __builtin_nontemporal_store(v2 * gv, &op[tid + 512]);
  if (tid < 16) {
    f4 v3 = xp[tid + 768];
    __builtin_nontemporal_store(v3 * gv, &op[tid + 768]);
  }
}

extern "C" void kernel_launch(void* const* d_in, const int* in_sizes, int n_in,
                              void* d_out, int out_size, void* d_ws, size_t ws_size,
                              hipStream_t stream) {
  const float* x      = (const float*)d_in[0];
  const float* gc_w   = (const float*)d_in[1];
  // d_in[2] = gc_b: softmax shift-invariant, unused
  const float* lc_w   = (const float*)d_in[3];
  const float* lc_b   = (const float*)d_in[4];
  const float* lcln_g = (const float*)d_in[5];
  const float* lcln_b = (const float*)d_in[6];
  const float* tw_w   = (const float*)d_in[7];
  const float* tw_b   = (const float*)d_in[8];
  const float* twln_g = (const float*)d_in[9];
  const float* twln_b = (const float*)d_in[10];
  const float* wdct   = (const float*)d_in[11];
  const float* wmax   = (const float*)d_in[12];
  float* out = (float*)d_out;

  float* ws    = (float*)d_ws;
  float* lpart = ws;                                   // NCH*N*S
  float* attn  = lpart + (size_t)NCH * N_ * S_;        // N*S
  float* xg    = attn + (size_t)N_ * S_;               // N*C
  float* xmax_ = xg + N_ * C_;
  float* xdct_ = xmax_ + N_ * C_;
  float* gate  = xdct_ + N_ * C_;

  hipLaunchKernelGGL(k_logits, dim3(NCH, N_, SQ), dim3(256), 0, stream, x, gc_w, lpart);
  hipLaunchKernelGGL(k_softmax, dim3(N_), dim3(256), 0, stream, lpart, attn);
  hipLaunchKernelGGL(k_stats, dim3(C_, N_), dim3(256), 0, stream, x, attn, xg, xmax_, xdct_);
  hipLaunchKernelGGL(k_gate, dim3(N_), dim3(1024), 0, stream,
                     xg, xmax_, xdct_, lc_w, lc_b, lcln_g, lcln_b,
                     tw_w, tw_b, twln_g, twln_b, wdct, wmax, gate);
  hipLaunchKernelGGL(k_scale, dim3(C_, N_), dim3(256), 0, stream, x, gate, out);
}